// Round 19
// baseline (207.273 us; speedup 1.0000x reference)
//
#include <hip/hip_runtime.h>
#include <hip/hip_bf16.h>
#include <hip/hip_fp8.h>

#define NB 8
#define NP 8192
#define IMH 512
#define IMW 512
#define NC 192
#define FH 128
#define FW 128
#define NSTATE 256

#define P1 232   // bf16 K-pitch for X (K padded to 224); 116 dw, bank-balanced
#define P2 264   // bf16 K-pitch for H1 (K=256); 132 dw, bank-balanced
#define CPITCH 72  // conv im2col LDS pitch
#define W1FRAG 57344  // 7 kc x 16 ngrp x 64 lane x 8 (fragment-major W1 layer)
#define W2FRAG 65536  // 8 kc x 16 ngrp x 64 lane x 8

typedef __attribute__((ext_vector_type(8))) unsigned short ush8;
typedef __attribute__((ext_vector_type(8))) short short8v;
typedef __attribute__((ext_vector_type(4))) float f32x4;

__device__ __forceinline__ float fp8tof(unsigned char b) {
  __hip_fp8_e4m3 v;
  v.__x = b;
  return (float)v;
}
__device__ __forceinline__ unsigned char ftofp8(float f) {
  __hip_fp8_e4m3 v(f);
  return v.__x;
}
// RNE f32 -> bf16 bits (matches __float2bfloat16 for finite values)
__device__ __forceinline__ unsigned short f2bf(float f) {
  const unsigned u = __float_as_uint(f);
  return (unsigned short)((u + 0x7fffu + ((u >> 16) & 1u)) >> 16);
}
// byte e of a uint4 (e compile-time under unroll -> pure register shifts)
__device__ __forceinline__ unsigned getb(uint4 v, int e) {
  const unsigned d = (e < 4) ? v.x : (e < 8) ? v.y : (e < 12) ? v.z : v.w;
  return (d >> ((e & 3) * 8)) & 0xffu;
}
// monotone float<->uint encoding: min on floats == min on encoded uints
__device__ __forceinline__ unsigned fenc(float f) {
  unsigned u = __float_as_uint(f);
  return (u & 0x80000000u) ? ~u : (u | 0x80000000u);
}
__device__ __forceinline__ float fdec(unsigned u) {
  return __uint_as_float((u & 0x80000000u) ? (u & 0x7FFFFFFFu) : ~u);
}

// ---------------- conv as MFMA GEMM -> feat fp8 [b][pix][192] ----------------
__global__ __launch_bounds__(256) void conv_kernel(
    const float* __restrict__ img, const __hip_bfloat16* __restrict__ wcb,
    const float* __restrict__ bb, unsigned char* __restrict__ feat) {
  __shared__ __hip_bfloat16 Xim[64 * CPITCH];  // 9 KB

  const int tid = threadIdx.x;
  const int lane = tid & 63;
  const int w = tid >> 6;
  const int cl = lane & 15;
  const int kg = lane >> 4;
  const int b = blockIdx.x & 7;
  const int pix0 = (blockIdx.x >> 3) * 64;
  const int y = pix0 >> 7;
  const int xh = (pix0 >> 6) & 1;

  {
    const int pix = tid & 63;
    const int q = tid >> 6;
    *(uint2*)&Xim[pix * CPITCH + 48 + q * 4] = (uint2){0u, 0u};
  }

#pragma unroll
  for (int it = 0; it < 3; ++it) {
    const int idx = it * 256 + tid;  // 0..767
    const int row = idx >> 6;        // ci*4+ky
    const int c = idx & 63;          // local pixel
    const int ci = row >> 2, ky = row & 3;
    const float4 v = *(const float4*)(img + (((size_t)b * 3 + ci) * IMH +
                                             (y * 4 + ky)) * IMW + xh * 256 + c * 4);
    // pack 4 bf16 directly into two dwords (no address-taken locals)
    unsigned lo = (unsigned)f2bf(v.x) | ((unsigned)f2bf(v.y) << 16);
    unsigned hi = (unsigned)f2bf(v.z) | ((unsigned)f2bf(v.w) << 16);
    *(uint2*)&Xim[c * CPITCH + ci * 16 + ky * 4] = (uint2){lo, hi};
  }
  __syncthreads();

  f32x4 acc[4][3];
#pragma unroll
  for (int mt = 0; mt < 4; ++mt)
#pragma unroll
    for (int nt = 0; nt < 3; ++nt) acc[mt][nt] = (f32x4){0, 0, 0, 0};

#pragma unroll
  for (int kc = 0; kc < 2; ++kc) {
    short8v af[4], bfv[3];
#pragma unroll
    for (int mt = 0; mt < 4; ++mt)
      af[mt] = *(const short8v*)&Xim[(mt * 16 + cl) * CPITCH + kc * 32 + kg * 8];
#pragma unroll
    for (int nt = 0; nt < 3; ++nt)
      bfv[nt] = *(const short8v*)&wcb[(size_t)(w * 48 + nt * 16 + cl) * 64 +
                                      kc * 32 + kg * 8];
#pragma unroll
    for (int mt = 0; mt < 4; ++mt)
#pragma unroll
      for (int nt = 0; nt < 3; ++nt)
        acc[mt][nt] = __builtin_amdgcn_mfma_f32_16x16x32_bf16(
            af[mt], bfv[nt], acc[mt][nt], 0, 0, 0);
  }

#pragma unroll
  for (int nt = 0; nt < 3; ++nt) {
    const float bias = bb[w * 48 + nt * 16 + cl];
#pragma unroll
    for (int mt = 0; mt < 4; ++mt) {
#pragma unroll
      for (int r = 0; r < 4; ++r) {
        feat[((size_t)b * 16384 + pix0 + mt * 16 + kg * 4 + r) * 192 +
             w * 48 + nt * 16 + cl] = ftofp8(acc[mt][nt][r] + bias);
      }
    }
  }
}

// ---------------- weight prep: FRAGMENT-MAJOR layout + mins ----------------
__global__ void prep_all_kernel(
    const float* __restrict__ oW1, const float* __restrict__ cW1,
    const float* __restrict__ oW2, const float* __restrict__ cW2,
    const float* __restrict__ bw, const float* __restrict__ pred,
    const float* __restrict__ mask, __hip_bfloat16* __restrict__ w1c,
    __hip_bfloat16* __restrict__ w2c, __hip_bfloat16* __restrict__ wcb,
    unsigned* __restrict__ mins4) {
  __shared__ float sx[4], sy[4];
  const int idx = blockIdx.x * 256 + threadIdx.x;
  const int region = blockIdx.y;
  if (region == 0) {
    if (idx >= 4 * W1FRAG) return;
    const int L = idx / W1FRAG;
    const int rem = idx - L * W1FRAG;
    const int kc = rem >> 13;
    const int r2 = rem & 8191;
    const int ng = r2 >> 9;
    const int r3 = r2 & 511;
    const int lane = r3 >> 3;
    const int e = r3 & 7;
    const int n = ng * 16 + (lane & 15);
    const int k = kc * 32 + (lane >> 4) * 8 + e;
    const float* src = (L < 3) ? (oW1 + (size_t)L * 256 * 194) : cW1;
    const int K = (L < 3) ? 194 : 195;
    w1c[idx] = __float2bfloat16((k < K) ? src[(size_t)n * K + k] : 0.0f);
  } else if (region == 1) {
    if (idx >= 4 * W2FRAG) return;
    const int L = idx >> 16;
    const int rem = idx & 65535;
    const int kc = rem >> 13;
    const int r2 = rem & 8191;
    const int ng = r2 >> 9;
    const int r3 = r2 & 511;
    const int lane = r3 >> 3;
    const int e = r3 & 7;
    const int n = ng * 16 + (lane & 15);
    const int k = kc * 32 + (lane >> 4) * 8 + e;
    const float* src = (L < 3) ? (oW2 + (size_t)L * 65536) : cW2;
    w2c[idx] = __float2bfloat16(src[(size_t)n * 256 + k]);
  } else if (region == 2) {
    if (idx < 48) mins4[16 + idx] = fenc(1e9f);  // slots 1..3
    if (idx >= 192 * 64) return;
    const int n = idx >> 6;
    const int k = idx & 63;
    wcb[idx] = __float2bfloat16((k < 48) ? bw[(size_t)n * 48 + k] : 0.0f);
  } else {
    if (blockIdx.x >= 8) return;
    const int b = blockIdx.x;
    float mx = 1e9f, my = 1e9f;
    for (int n = threadIdx.x; n < NP; n += 256) {
      float m = mask[(size_t)b * NP + n];
      float2 p = *(const float2*)&pred[((size_t)b * NP + n) * 2];
      mx = fminf(mx, m > 0.0f ? p.x : 1e9f);
      my = fminf(my, m > 0.0f ? p.y : 1e9f);
    }
#pragma unroll
    for (int o = 32; o > 0; o >>= 1) {
      mx = fminf(mx, __shfl_down(mx, o));
      my = fminf(my, __shfl_down(my, o));
    }
    if ((threadIdx.x & 63) == 0) {
      sx[threadIdx.x >> 6] = mx;
      sy[threadIdx.x >> 6] = my;
    }
    __syncthreads();
    if (threadIdx.x == 0) {
      mx = fminf(fminf(sx[0], sx[1]), fminf(sx[2], sx[3]));
      my = fminf(fminf(sy[0], sy[1]), fminf(sy[2], sy[3]));
      mins4[b * 2 + 0] = fenc(mx);
      mins4[b * 2 + 1] = fenc(my);
    }
  }
}

// ---------------- fused gather (fp8 feat, row-contiguous) + MFMA MLP ----
// Round-15 structure with ALL address-taken locals / union punning removed
// from the gather path (dword-shift byte extraction + element-wise ush8
// construction) to eliminate the per-thread scratch lowering.
template <bool CLS>
__global__ __launch_bounds__(256, 2) void mlp_kernel(
    const unsigned char* __restrict__ feat,
    const float* __restrict__ p_in,
    const float* __restrict__ mask,
    const unsigned* __restrict__ mins_in,
    unsigned* __restrict__ mins_out,
    const __hip_bfloat16* __restrict__ W1c, const float* __restrict__ b1,
    const __hip_bfloat16* __restrict__ W2c, const float* __restrict__ b2,
    const float* __restrict__ W3, const float* __restrict__ b3,
    float* __restrict__ out0) {
  __shared__ __hip_bfloat16 Xls[64 * P2];  // X[64][P1] then H1[64][P2]
  __shared__ float red[4][64][2];

  const int tid = threadIdx.x;
  const int lane = tid & 63;
  const int w = tid >> 6;
  const int cl = lane & 15;
  const int kg = lane >> 4;
  const int b = blockIdx.x & 7;             // XCD-aligned batch
  const int m0 = (blockIdx.x >> 3) * 64;

  // ---- gather: thread = (point m = tid>>2, 16B slot s = tid&3) ----
  {
    const int m = tid >> 2;
    const int s = tid & 3;
    const int n = m0 + m;
    const size_t pidx = (size_t)b * NP + n;
    const float msk = mask[pidx];
    const float2 pv = *(const float2*)&p_in[pidx * 2];
    const float px = pv.x, pyv = pv.y;
    const float xs = px * (127.0f / 128.0f);
    const float ys = pyv * (127.0f / 128.0f);
    const float x0f = floorf(xs), y0f = floorf(ys);
    const float fx = xs - x0f, fy = ys - y0f;
    const int x0 = (int)fminf(fmaxf(x0f, 0.0f), 127.0f);
    const int x1 = (int)fminf(fmaxf(x0f + 1.0f, 0.0f), 127.0f);
    const int y0 = (int)fminf(fmaxf(y0f, 0.0f), 127.0f);
    const int y1 = (int)fminf(fmaxf(y0f + 1.0f, 0.0f), 127.0f);
    const float w00 = (1.0f - fy) * (1.0f - fx);
    const float w01 = (1.0f - fy) * fx;
    const float w10 = fy * (1.0f - fx);
    const float w11 = fy * fx;
    const unsigned char* fb = feat + (size_t)b * 16384 * 192 + s * 16;
    const unsigned char* r00 = fb + (size_t)(y0 * FW + x0) * 192;
    const unsigned char* r01 = fb + (size_t)(y0 * FW + x1) * 192;
    const unsigned char* r10 = fb + (size_t)(y1 * FW + x0) * 192;
    const unsigned char* r11 = fb + (size_t)(y1 * FW + x1) * 192;
#pragma unroll
    for (int v = 0; v < 3; ++v) {
      const uint4 a0 = *(const uint4*)(r00 + v * 64);
      const uint4 a1 = *(const uint4*)(r01 + v * 64);
      const uint4 a2 = *(const uint4*)(r10 + v * 64);
      const uint4 a3 = *(const uint4*)(r11 + v * 64);
      ush8 hlo, hhi;
#pragma unroll
      for (int e = 0; e < 8; ++e) {
        const float gg = w00 * fp8tof(getb(a0, e)) + w01 * fp8tof(getb(a1, e)) +
                         w10 * fp8tof(getb(a2, e)) + w11 * fp8tof(getb(a3, e));
        hlo[e] = f2bf(gg * msk);
      }
#pragma unroll
      for (int e = 8; e < 16; ++e) {
        const float gg = w00 * fp8tof(getb(a0, e)) + w01 * fp8tof(getb(a1, e)) +
                         w10 * fp8tof(getb(a2, e)) + w11 * fp8tof(getb(a3, e));
        hhi[e - 8] = f2bf(gg * msk);
      }
      *(ush8*)&Xls[m * P1 + v * 64 + s * 16 + 0] = hlo;
      *(ush8*)&Xls[m * P1 + v * 64 + s * 16 + 8] = hhi;
    }
    if (s == 0) {
      ush8 ex0 = (ush8){0, 0, 0, 0, 0, 0, 0, 0};
      const ush8 exz = (ush8){0, 0, 0, 0, 0, 0, 0, 0};
      if constexpr (!CLS) {
        ex0[0] = f2bf((px - fdec(mins_in[b * 2 + 0])) * msk);
        ex0[1] = f2bf((pyv - fdec(mins_in[b * 2 + 1])) * msk);
      } else {
        ex0[0] = f2bf(px);
        ex0[1] = f2bf(pyv);
        const int npv = (n + NP - 1) & (NP - 1);
        const int nnx = (n + 1) & (NP - 1);
        const float2 pp = *(const float2*)&p_in[((size_t)b * NP + npv) * 2];
        const float2 pn = *(const float2*)&p_in[((size_t)b * NP + nnx) * 2];
        const float v1x = pp.x - px, v1y = pp.y - pyv;
        const float v2x = pn.x - px, v2y = pn.y - pyv;
        const float dot = v1x * v2x + v1y * v2y;
        const float nrm =
            sqrtf(v1x * v1x + v1y * v1y) * sqrtf(v2x * v2x + v2y * v2y);
        const float ca = fminf(fmaxf(dot / (nrm + 1e-8f), -1.0f), 1.0f);
        ex0[2] = f2bf(acosf(ca) * msk);
      }
      *(ush8*)&Xls[m * P1 + 192] = ex0;
      *(ush8*)&Xls[m * P1 + 200] = exz;
      *(ush8*)&Xls[m * P1 + 208] = exz;
      *(ush8*)&Xls[m * P1 + 216] = exz;
    }
  }

  // epilogue scalars (small)
  float b1v[4], b2v[4], w3av[4], w3bv[4];
#pragma unroll
  for (int nt = 0; nt < 4; ++nt) {
    const int n = w * 64 + nt * 16 + cl;
    b1v[nt] = b1[n];
    b2v[nt] = b2[n];
    w3av[nt] = W3[n];
    w3bv[nt] = CLS ? 0.0f : W3[256 + n];
  }
  __syncthreads();

  // ---- GEMM1: in-loop coalesced W1 fragment loads ----
  f32x4 acc[4][4];
#pragma unroll
  for (int mt = 0; mt < 4; ++mt)
#pragma unroll
    for (int nt = 0; nt < 4; ++nt) acc[mt][nt] = (f32x4){0, 0, 0, 0};

#pragma unroll
  for (int kc = 0; kc < 7; ++kc) {
    short8v af[4], bfv[4];
#pragma unroll
    for (int nt = 0; nt < 4; ++nt)
      bfv[nt] = *(const short8v*)&W1c[kc * 8192 + (w * 4 + nt) * 512 + lane * 8];
#pragma unroll
    for (int mt = 0; mt < 4; ++mt)
      af[mt] = *(const short8v*)&Xls[(mt * 16 + cl) * P1 + kc * 32 + kg * 8];
#pragma unroll
    for (int mt = 0; mt < 4; ++mt)
#pragma unroll
      for (int nt = 0; nt < 4; ++nt)
        acc[mt][nt] = __builtin_amdgcn_mfma_f32_16x16x32_bf16(
            af[mt], bfv[nt], acc[mt][nt], 0, 0, 0);
  }
  __syncthreads();  // Xls X-view no longer needed

  // H1 (bias+relu, bf16 bits) -> Xls as [m][P2]
#pragma unroll
  for (int nt = 0; nt < 4; ++nt) {
    const float bias = b1v[nt];
    const int n = w * 64 + nt * 16 + cl;
#pragma unroll
    for (int mt = 0; mt < 4; ++mt) {
#pragma unroll
      for (int r = 0; r < 4; ++r) {
        const float v = fmaxf(acc[mt][nt][r] + bias, 0.0f);
        *(unsigned short*)&Xls[(mt * 16 + kg * 4 + r) * P2 + n] = f2bf(v);
      }
    }
  }
  __syncthreads();

  // ---- GEMM2: in-loop coalesced W2 fragment loads ----
  f32x4 acc2[4][4];
#pragma unroll
  for (int mt = 0; mt < 4; ++mt)
#pragma unroll
    for (int nt = 0; nt < 4; ++nt) acc2[mt][nt] = (f32x4){0, 0, 0, 0};

#pragma unroll
  for (int kc = 0; kc < 8; ++kc) {
    short8v af[4], bfv[4];
#pragma unroll
    for (int nt = 0; nt < 4; ++nt)
      bfv[nt] = *(const short8v*)&W2c[kc * 8192 + (w * 4 + nt) * 512 + lane * 8];
#pragma unroll
    for (int mt = 0; mt < 4; ++mt)
      af[mt] = *(const short8v*)&Xls[(mt * 16 + cl) * P2 + kc * 32 + kg * 8];
#pragma unroll
    for (int mt = 0; mt < 4; ++mt)
#pragma unroll
      for (int nt = 0; nt < 4; ++nt)
        acc2[mt][nt] = __builtin_amdgcn_mfma_f32_16x16x32_bf16(
            af[mt], bfv[nt], acc2[mt][nt], 0, 0, 0);
  }

  // ---- GEMM3 (f32) + reduction + epilogue ----
  float pr0[4][4], pr1[4][4];
#pragma unroll
  for (int mt = 0; mt < 4; ++mt)
#pragma unroll
    for (int r = 0; r < 4; ++r) { pr0[mt][r] = 0.0f; pr1[mt][r] = 0.0f; }

#pragma unroll
  for (int nt = 0; nt < 4; ++nt) {
    const float bias = b2v[nt];
    const float w3a = w3av[nt];
    const float w3b = w3bv[nt];
#pragma unroll
    for (int mt = 0; mt < 4; ++mt) {
#pragma unroll
      for (int r = 0; r < 4; ++r) {
        const float t = fmaxf(acc2[mt][nt][r] + bias, 0.0f);
        pr0[mt][r] = fmaf(t, w3a, pr0[mt][r]);
        if constexpr (!CLS) pr1[mt][r] = fmaf(t, w3b, pr1[mt][r]);
      }
    }
  }
#pragma unroll
  for (int s = 1; s < 16; s <<= 1) {
#pragma unroll
    for (int mt = 0; mt < 4; ++mt)
#pragma unroll
      for (int r = 0; r < 4; ++r) {
        pr0[mt][r] += __shfl_xor(pr0[mt][r], s);
        if constexpr (!CLS) pr1[mt][r] += __shfl_xor(pr1[mt][r], s);
      }
  }
  if constexpr (!CLS) {
    if (cl < 8) {
      const int r = cl >> 1, o = cl & 1;
#pragma unroll
      for (int mt = 0; mt < 4; ++mt)
        red[w][mt * 16 + kg * 4 + r][o] = (o == 0) ? pr0[mt][r] : pr1[mt][r];
    }
  } else {
    if (cl < 4) {
      const int r = cl;
#pragma unroll
      for (int mt = 0; mt < 4; ++mt)
        red[w][mt * 16 + kg * 4 + r][0] = pr0[mt][r];
    }
  }
  __syncthreads();

  if constexpr (!CLS) {
    if (tid < 128) {
      const int m = tid >> 1, o = tid & 1;
      const float s = red[0][m][o] + red[1][m][o] + red[2][m][o] + red[3][m][o];
      const size_t pidx = (size_t)b * NP + m0 + m;
      const float msk = mask[pidx];
      const float off = (s + b3[o]) * msk;
      const float nv = p_in[pidx * 2 + o] + off * 4.0f;
      out0[pidx * 2 + o] = nv;
      float mval = (msk > 0.0f) ? nv : 1e9f;
#pragma unroll
      for (int st = 2; st < 64; st <<= 1)
        mval = fminf(mval, __shfl_xor(mval, st));
      if ((tid & 63) < 2 && mins_out != nullptr)
        atomicMin(&mins_out[b * 2 + o], fenc(mval));
    }
  } else {
    if (tid < 64) {
      const int m = tid;
      const float s = red[0][m][0] + red[1][m][0] + red[2][m][0] + red[3][m][0];
      const size_t pidx = (size_t)b * NP + m0 + m;
      const float msk = mask[pidx];
      out0[pidx * 2 + 0] = p_in[pidx * 2 + 0] * 4.0f;
      out0[pidx * 2 + 1] = p_in[pidx * 2 + 1] * 4.0f;
      out0[(size_t)2 * NB * NP + pidx] = (s + b3[0]) * msk;
    }
  }
}

extern "C" void kernel_launch(void* const* d_in, const int* in_sizes, int n_in,
                              void* d_out, int out_size, void* d_ws,
                              size_t ws_size, hipStream_t stream) {
  const float* image = (const float*)d_in[0];
  const float* pred  = (const float*)d_in[1];
  const float* mask  = (const float*)d_in[2];
  const float* bw    = (const float*)d_in[3];
  const float* bb    = (const float*)d_in[4];
  const float* oW1   = (const float*)d_in[5];
  const float* ob1   = (const float*)d_in[6];
  const float* oW2   = (const float*)d_in[7];
  const float* ob2   = (const float*)d_in[8];
  const float* oW3   = (const float*)d_in[9];
  const float* ob3   = (const float*)d_in[10];
  const float* cW1   = (const float*)d_in[11];
  const float* cb1   = (const float*)d_in[12];
  const float* cW2   = (const float*)d_in[13];
  const float* cb2   = (const float*)d_in[14];
  const float* cW3   = (const float*)d_in[15];
  const float* cb3   = (const float*)d_in[16];
  float* out = (float*)d_out;

  char* ws = (char*)d_ws;
  unsigned char* feat = (unsigned char*)ws;                // fp8, 25.2 MB
  const size_t featB = (size_t)NB * FH * FW * NC;
  float* pyA  = (float*)(ws + featB);
  float* pyB  = pyA + (size_t)NB * NP * 2;
  unsigned* mins4 = (unsigned*)(pyB + (size_t)NB * NP * 2);  // [4][16] encoded
  __hip_bfloat16* w1c = (__hip_bfloat16*)(mins4 + 64);    // 4 x W1FRAG
  __hip_bfloat16* w2c = w1c + (size_t)4 * W1FRAG;         // 4 x W2FRAG
  __hip_bfloat16* wcb = w2c + (size_t)4 * W2FRAG;         // [192][64]

  prep_all_kernel<<<dim3(1024, 4), 256, 0, stream>>>(
      oW1, cW1, oW2, cW2, bw, pred, mask, w1c, w2c, wcb, mins4);
  conv_kernel<<<dim3(NB * 16384 / 64), 256, 0, stream>>>(image, wcb, bb, feat);

  const float* cur = pred;
  float* nxt = pyA;
  for (int i = 0; i < 3; ++i) {
    mlp_kernel<false><<<dim3(NB * NP / 64), 256, 0, stream>>>(
        feat, cur, mask, mins4 + i * 16,
        (i < 2) ? (mins4 + (i + 1) * 16) : nullptr,
        w1c + (size_t)i * W1FRAG, ob1 + (size_t)i * NSTATE,
        w2c + (size_t)i * W2FRAG, ob2 + (size_t)i * NSTATE,
        oW3 + (size_t)i * 2 * NSTATE, ob3 + (size_t)i * 2, nxt);
    cur = nxt;
    nxt = (nxt == pyA) ? pyB : pyA;
  }
  mlp_kernel<true><<<dim3(NB * NP / 64), 256, 0, stream>>>(
      feat, cur, mask, nullptr, nullptr, w1c + (size_t)3 * W1FRAG, cb1,
      w2c + (size_t)3 * W2FRAG, cb2, cW3, cb3, out);
}

// Round 20
// 186.137 us; speedup vs baseline: 1.1135x; 1.1135x over previous
//
#include <hip/hip_runtime.h>
#include <hip/hip_bf16.h>
#include <hip/hip_fp8.h>

#define NB 8
#define NP 8192
#define IMH 512
#define IMW 512
#define NC 192
#define FH 128
#define FW 128
#define NSTATE 256

#define P1 232   // bf16 K-pitch for X (K padded to 224); 116 dw, bank-balanced
#define P2 264   // bf16 K-pitch for H1 (K=256); 132 dw, bank-balanced
#define CPITCH 72  // conv im2col LDS pitch
#define W1FRAG 57344  // 7 kc x 16 ngrp x 64 lane x 8 (fragment-major W1 layer)
#define W2FRAG 65536  // 8 kc x 16 ngrp x 64 lane x 8

typedef __attribute__((ext_vector_type(8))) unsigned short ush8;
typedef __attribute__((ext_vector_type(8))) short short8v;
typedef __attribute__((ext_vector_type(4))) float f32x4;

__device__ __forceinline__ float fp8tof(unsigned char b) {
  __hip_fp8_e4m3 v;
  v.__x = b;
  return (float)v;
}
__device__ __forceinline__ unsigned char ftofp8(float f) {
  __hip_fp8_e4m3 v(f);
  return v.__x;
}
// monotone float<->uint encoding: min on floats == min on encoded uints
__device__ __forceinline__ unsigned fenc(float f) {
  unsigned u = __float_as_uint(f);
  return (u & 0x80000000u) ? ~u : (u | 0x80000000u);
}
__device__ __forceinline__ float fdec(unsigned u) {
  return __uint_as_float((u & 0x80000000u) ? (u & 0x7FFFFFFFu) : ~u);
}

// ---------------- conv as MFMA GEMM -> feat fp8 [b][pix][192] ----------------
__global__ __launch_bounds__(256) void conv_kernel(
    const float* __restrict__ img, const __hip_bfloat16* __restrict__ wcb,
    const float* __restrict__ bb, unsigned char* __restrict__ feat) {
  __shared__ __hip_bfloat16 Xim[64 * CPITCH];  // 9 KB

  const int tid = threadIdx.x;
  const int lane = tid & 63;
  const int w = tid >> 6;
  const int cl = lane & 15;
  const int kg = lane >> 4;
  const int b = blockIdx.x & 7;
  const int pix0 = (blockIdx.x >> 3) * 64;
  const int y = pix0 >> 7;
  const int xh = (pix0 >> 6) & 1;

  {
    const int pix = tid & 63;
    const int q = tid >> 6;
    *(uint2*)&Xim[pix * CPITCH + 48 + q * 4] = (uint2){0u, 0u};
  }

#pragma unroll
  for (int it = 0; it < 3; ++it) {
    const int idx = it * 256 + tid;  // 0..767
    const int row = idx >> 6;        // ci*4+ky
    const int c = idx & 63;          // local pixel
    const int ci = row >> 2, ky = row & 3;
    const float4 v = *(const float4*)(img + (((size_t)b * 3 + ci) * IMH +
                                             (y * 4 + ky)) * IMW + xh * 256 + c * 4);
    __hip_bfloat16 h[4];
    h[0] = __float2bfloat16(v.x);
    h[1] = __float2bfloat16(v.y);
    h[2] = __float2bfloat16(v.z);
    h[3] = __float2bfloat16(v.w);
    *(uint2*)&Xim[c * CPITCH + ci * 16 + ky * 4] = *(const uint2*)h;
  }
  __syncthreads();

  f32x4 acc[4][3];
#pragma unroll
  for (int mt = 0; mt < 4; ++mt)
#pragma unroll
    for (int nt = 0; nt < 3; ++nt) acc[mt][nt] = (f32x4){0, 0, 0, 0};

#pragma unroll
  for (int kc = 0; kc < 2; ++kc) {
    short8v af[4], bfv[3];
#pragma unroll
    for (int mt = 0; mt < 4; ++mt)
      af[mt] = *(const short8v*)&Xim[(mt * 16 + cl) * CPITCH + kc * 32 + kg * 8];
#pragma unroll
    for (int nt = 0; nt < 3; ++nt)
      bfv[nt] = *(const short8v*)&wcb[(size_t)(w * 48 + nt * 16 + cl) * 64 +
                                      kc * 32 + kg * 8];
#pragma unroll
    for (int mt = 0; mt < 4; ++mt)
#pragma unroll
      for (int nt = 0; nt < 3; ++nt)
        acc[mt][nt] = __builtin_amdgcn_mfma_f32_16x16x32_bf16(
            af[mt], bfv[nt], acc[mt][nt], 0, 0, 0);
  }

#pragma unroll
  for (int nt = 0; nt < 3; ++nt) {
    const float bias = bb[w * 48 + nt * 16 + cl];
#pragma unroll
    for (int mt = 0; mt < 4; ++mt) {
#pragma unroll
      for (int r = 0; r < 4; ++r) {
        feat[((size_t)b * 16384 + pix0 + mt * 16 + kg * 4 + r) * 192 +
             w * 48 + nt * 16 + cl] = ftofp8(acc[mt][nt][r] + bias);
      }
    }
  }
}

// ---------------- weight prep: FRAGMENT-MAJOR layout + mins ----------------
__global__ void prep_all_kernel(
    const float* __restrict__ oW1, const float* __restrict__ cW1,
    const float* __restrict__ oW2, const float* __restrict__ cW2,
    const float* __restrict__ bw, const float* __restrict__ pred,
    const float* __restrict__ mask, __hip_bfloat16* __restrict__ w1c,
    __hip_bfloat16* __restrict__ w2c, __hip_bfloat16* __restrict__ wcb,
    unsigned* __restrict__ mins4) {
  __shared__ float sx[4], sy[4];
  const int idx = blockIdx.x * 256 + threadIdx.x;
  const int region = blockIdx.y;
  if (region == 0) {
    if (idx >= 4 * W1FRAG) return;
    const int L = idx / W1FRAG;
    const int rem = idx - L * W1FRAG;
    const int kc = rem >> 13;
    const int r2 = rem & 8191;
    const int ng = r2 >> 9;
    const int r3 = r2 & 511;
    const int lane = r3 >> 3;
    const int e = r3 & 7;
    const int n = ng * 16 + (lane & 15);
    const int k = kc * 32 + (lane >> 4) * 8 + e;
    const float* src = (L < 3) ? (oW1 + (size_t)L * 256 * 194) : cW1;
    const int K = (L < 3) ? 194 : 195;
    w1c[idx] = __float2bfloat16((k < K) ? src[(size_t)n * K + k] : 0.0f);
  } else if (region == 1) {
    if (idx >= 4 * W2FRAG) return;
    const int L = idx >> 16;
    const int rem = idx & 65535;
    const int kc = rem >> 13;
    const int r2 = rem & 8191;
    const int ng = r2 >> 9;
    const int r3 = r2 & 511;
    const int lane = r3 >> 3;
    const int e = r3 & 7;
    const int n = ng * 16 + (lane & 15);
    const int k = kc * 32 + (lane >> 4) * 8 + e;
    const float* src = (L < 3) ? (oW2 + (size_t)L * 65536) : cW2;
    w2c[idx] = __float2bfloat16(src[(size_t)n * 256 + k]);
  } else if (region == 2) {
    if (idx < 48) mins4[16 + idx] = fenc(1e9f);  // slots 1..3
    if (idx >= 192 * 64) return;
    const int n = idx >> 6;
    const int k = idx & 63;
    wcb[idx] = __float2bfloat16((k < 48) ? bw[(size_t)n * 48 + k] : 0.0f);
  } else {
    if (blockIdx.x >= 8) return;
    const int b = blockIdx.x;
    float mx = 1e9f, my = 1e9f;
    for (int n = threadIdx.x; n < NP; n += 256) {
      float m = mask[(size_t)b * NP + n];
      float2 p = *(const float2*)&pred[((size_t)b * NP + n) * 2];
      mx = fminf(mx, m > 0.0f ? p.x : 1e9f);
      my = fminf(my, m > 0.0f ? p.y : 1e9f);
    }
#pragma unroll
    for (int o = 32; o > 0; o >>= 1) {
      mx = fminf(mx, __shfl_down(mx, o));
      my = fminf(my, __shfl_down(my, o));
    }
    if ((threadIdx.x & 63) == 0) {
      sx[threadIdx.x >> 6] = mx;
      sy[threadIdx.x >> 6] = my;
    }
    __syncthreads();
    if (threadIdx.x == 0) {
      mx = fminf(fminf(sx[0], sx[1]), fminf(sx[2], sx[3]));
      my = fminf(fminf(sy[0], sy[1]), fminf(sy[2], sy[3]));
      mins4[b * 2 + 0] = fenc(mx);
      mins4[b * 2 + 1] = fenc(my);
    }
  }
}

// ---------------- fused gather (fp8 feat, row-contiguous) + MFMA MLP ----
// Best-measured configuration (rounds 15/18): coalesced gather (192B rows),
// fragment-major in-loop weight loads, launch_bounds(256,2).
template <bool CLS>
__global__ __launch_bounds__(256, 2) void mlp_kernel(
    const unsigned char* __restrict__ feat,
    const float* __restrict__ p_in,
    const float* __restrict__ mask,
    const unsigned* __restrict__ mins_in,
    unsigned* __restrict__ mins_out,
    const __hip_bfloat16* __restrict__ W1c, const float* __restrict__ b1,
    const __hip_bfloat16* __restrict__ W2c, const float* __restrict__ b2,
    const float* __restrict__ W3, const float* __restrict__ b3,
    float* __restrict__ out0) {
  __shared__ __hip_bfloat16 Xls[64 * P2];  // X[64][P1] then H1[64][P2]
  __shared__ float red[4][64][2];

  const int tid = threadIdx.x;
  const int lane = tid & 63;
  const int w = tid >> 6;
  const int cl = lane & 15;
  const int kg = lane >> 4;
  const int b = blockIdx.x & 7;             // XCD-aligned batch
  const int m0 = (blockIdx.x >> 3) * 64;

  // ---- gather: thread = (point m = tid>>2, 16B slot s = tid&3) ----
  {
    const int m = tid >> 2;
    const int s = tid & 3;
    const int n = m0 + m;
    const size_t pidx = (size_t)b * NP + n;
    const float msk = mask[pidx];
    const float2 pv = *(const float2*)&p_in[pidx * 2];
    const float px = pv.x, pyv = pv.y;
    const float xs = px * (127.0f / 128.0f);
    const float ys = pyv * (127.0f / 128.0f);
    const float x0f = floorf(xs), y0f = floorf(ys);
    const float fx = xs - x0f, fy = ys - y0f;
    const int x0 = (int)fminf(fmaxf(x0f, 0.0f), 127.0f);
    const int x1 = (int)fminf(fmaxf(x0f + 1.0f, 0.0f), 127.0f);
    const int y0 = (int)fminf(fmaxf(y0f, 0.0f), 127.0f);
    const int y1 = (int)fminf(fmaxf(y0f + 1.0f, 0.0f), 127.0f);
    const float w00 = (1.0f - fy) * (1.0f - fx);
    const float w01 = (1.0f - fy) * fx;
    const float w10 = fy * (1.0f - fx);
    const float w11 = fy * fx;
    const unsigned char* fb = feat + (size_t)b * 16384 * 192 + s * 16;
    const unsigned char* r00 = fb + (size_t)(y0 * FW + x0) * 192;
    const unsigned char* r01 = fb + (size_t)(y0 * FW + x1) * 192;
    const unsigned char* r10 = fb + (size_t)(y1 * FW + x0) * 192;
    const unsigned char* r11 = fb + (size_t)(y1 * FW + x1) * 192;
#pragma unroll
    for (int v = 0; v < 3; ++v) {
      union { uint4 u; unsigned char c[16]; } a0, a1, a2, a3;
      a0.u = *(const uint4*)(r00 + v * 64);
      a1.u = *(const uint4*)(r01 + v * 64);
      a2.u = *(const uint4*)(r10 + v * 64);
      a3.u = *(const uint4*)(r11 + v * 64);
      __hip_bfloat16 h[16];
#pragma unroll
      for (int e = 0; e < 16; ++e) {
        float gg = w00 * fp8tof(a0.c[e]) + w01 * fp8tof(a1.c[e]) +
                   w10 * fp8tof(a2.c[e]) + w11 * fp8tof(a3.c[e]);
        h[e] = __float2bfloat16(gg * msk);
      }
      *(ush8*)&Xls[m * P1 + v * 64 + s * 16 + 0] = *(const ush8*)&h[0];
      *(ush8*)&Xls[m * P1 + v * 64 + s * 16 + 8] = *(const ush8*)&h[8];
    }
    if (s == 0) {
      __hip_bfloat16 ex[32];
#pragma unroll
      for (int i = 0; i < 32; ++i) ex[i] = __float2bfloat16(0.0f);
      if constexpr (!CLS) {
        ex[0] = __float2bfloat16((px - fdec(mins_in[b * 2 + 0])) * msk);
        ex[1] = __float2bfloat16((pyv - fdec(mins_in[b * 2 + 1])) * msk);
      } else {
        ex[0] = __float2bfloat16(px);
        ex[1] = __float2bfloat16(pyv);
        const int npv = (n + NP - 1) & (NP - 1);
        const int nnx = (n + 1) & (NP - 1);
        const float2 pp = *(const float2*)&p_in[((size_t)b * NP + npv) * 2];
        const float2 pn = *(const float2*)&p_in[((size_t)b * NP + nnx) * 2];
        const float v1x = pp.x - px, v1y = pp.y - pyv;
        const float v2x = pn.x - px, v2y = pn.y - pyv;
        const float dot = v1x * v2x + v1y * v2y;
        const float nrm =
            sqrtf(v1x * v1x + v1y * v1y) * sqrtf(v2x * v2x + v2y * v2y);
        const float ca = fminf(fmaxf(dot / (nrm + 1e-8f), -1.0f), 1.0f);
        ex[2] = __float2bfloat16(acosf(ca) * msk);
      }
#pragma unroll
      for (int q = 0; q < 4; ++q)
        *(ush8*)&Xls[m * P1 + 192 + q * 8] = *(const ush8*)&ex[q * 8];
    }
  }

  // epilogue scalars (small)
  float b1v[4], b2v[4], w3av[4], w3bv[4];
#pragma unroll
  for (int nt = 0; nt < 4; ++nt) {
    const int n = w * 64 + nt * 16 + cl;
    b1v[nt] = b1[n];
    b2v[nt] = b2[n];
    w3av[nt] = W3[n];
    w3bv[nt] = CLS ? 0.0f : W3[256 + n];
  }
  __syncthreads();

  // ---- GEMM1: in-loop coalesced W1 fragment loads ----
  f32x4 acc[4][4];
#pragma unroll
  for (int mt = 0; mt < 4; ++mt)
#pragma unroll
    for (int nt = 0; nt < 4; ++nt) acc[mt][nt] = (f32x4){0, 0, 0, 0};

#pragma unroll
  for (int kc = 0; kc < 7; ++kc) {
    short8v af[4], bfv[4];
#pragma unroll
    for (int nt = 0; nt < 4; ++nt)
      bfv[nt] = *(const short8v*)&W1c[kc * 8192 + (w * 4 + nt) * 512 + lane * 8];
#pragma unroll
    for (int mt = 0; mt < 4; ++mt)
      af[mt] = *(const short8v*)&Xls[(mt * 16 + cl) * P1 + kc * 32 + kg * 8];
#pragma unroll
    for (int mt = 0; mt < 4; ++mt)
#pragma unroll
      for (int nt = 0; nt < 4; ++nt)
        acc[mt][nt] = __builtin_amdgcn_mfma_f32_16x16x32_bf16(
            af[mt], bfv[nt], acc[mt][nt], 0, 0, 0);
  }
  __syncthreads();  // Xls X-view no longer needed

  // H1 (bias+relu, bf16) -> Xls as [m][P2]
#pragma unroll
  for (int nt = 0; nt < 4; ++nt) {
    const float bias = b1v[nt];
    const int n = w * 64 + nt * 16 + cl;
#pragma unroll
    for (int mt = 0; mt < 4; ++mt) {
#pragma unroll
      for (int r = 0; r < 4; ++r) {
        const float v = fmaxf(acc[mt][nt][r] + bias, 0.0f);
        Xls[(mt * 16 + kg * 4 + r) * P2 + n] = __float2bfloat16(v);
      }
    }
  }
  __syncthreads();

  // ---- GEMM2: in-loop coalesced W2 fragment loads ----
  f32x4 acc2[4][4];
#pragma unroll
  for (int mt = 0; mt < 4; ++mt)
#pragma unroll
    for (int nt = 0; nt < 4; ++nt) acc2[mt][nt] = (f32x4){0, 0, 0, 0};

#pragma unroll
  for (int kc = 0; kc < 8; ++kc) {
    short8v af[4], bfv[4];
#pragma unroll
    for (int nt = 0; nt < 4; ++nt)
      bfv[nt] = *(const short8v*)&W2c[kc * 8192 + (w * 4 + nt) * 512 + lane * 8];
#pragma unroll
    for (int mt = 0; mt < 4; ++mt)
      af[mt] = *(const short8v*)&Xls[(mt * 16 + cl) * P2 + kc * 32 + kg * 8];
#pragma unroll
    for (int mt = 0; mt < 4; ++mt)
#pragma unroll
      for (int nt = 0; nt < 4; ++nt)
        acc2[mt][nt] = __builtin_amdgcn_mfma_f32_16x16x32_bf16(
            af[mt], bfv[nt], acc2[mt][nt], 0, 0, 0);
  }

  // ---- GEMM3 (f32) + reduction + epilogue ----
  float pr[4][4][2];
#pragma unroll
  for (int mt = 0; mt < 4; ++mt)
#pragma unroll
    for (int r = 0; r < 4; ++r) { pr[mt][r][0] = 0.0f; pr[mt][r][1] = 0.0f; }

#pragma unroll
  for (int nt = 0; nt < 4; ++nt) {
    const float bias = b2v[nt];
    const float w3a = w3av[nt];
    const float w3b = w3bv[nt];
#pragma unroll
    for (int mt = 0; mt < 4; ++mt) {
#pragma unroll
      for (int r = 0; r < 4; ++r) {
        const float t = fmaxf(acc2[mt][nt][r] + bias, 0.0f);
        pr[mt][r][0] = fmaf(t, w3a, pr[mt][r][0]);
        if constexpr (!CLS) pr[mt][r][1] = fmaf(t, w3b, pr[mt][r][1]);
      }
    }
  }
#pragma unroll
  for (int s = 1; s < 16; s <<= 1) {
#pragma unroll
    for (int mt = 0; mt < 4; ++mt)
#pragma unroll
      for (int r = 0; r < 4; ++r) {
        pr[mt][r][0] += __shfl_xor(pr[mt][r][0], s);
        if constexpr (!CLS) pr[mt][r][1] += __shfl_xor(pr[mt][r][1], s);
      }
  }
  if constexpr (!CLS) {
    if (cl < 8) {
      const int r = cl >> 1, o = cl & 1;
#pragma unroll
      for (int mt = 0; mt < 4; ++mt)
        red[w][mt * 16 + kg * 4 + r][o] = pr[mt][r][o];
    }
  } else {
    if (cl < 4) {
      const int r = cl;
#pragma unroll
      for (int mt = 0; mt < 4; ++mt)
        red[w][mt * 16 + kg * 4 + r][0] = pr[mt][r][0];
    }
  }
  __syncthreads();

  if constexpr (!CLS) {
    if (tid < 128) {
      const int m = tid >> 1, o = tid & 1;
      const float s = red[0][m][o] + red[1][m][o] + red[2][m][o] + red[3][m][o];
      const size_t pidx = (size_t)b * NP + m0 + m;
      const float msk = mask[pidx];
      const float off = (s + b3[o]) * msk;
      const float nv = p_in[pidx * 2 + o] + off * 4.0f;
      out0[pidx * 2 + o] = nv;
      float mval = (msk > 0.0f) ? nv : 1e9f;
#pragma unroll
      for (int st = 2; st < 64; st <<= 1)
        mval = fminf(mval, __shfl_xor(mval, st));
      if ((tid & 63) < 2 && mins_out != nullptr)
        atomicMin(&mins_out[b * 2 + o], fenc(mval));
    }
  } else {
    if (tid < 64) {
      const int m = tid;
      const float s = red[0][m][0] + red[1][m][0] + red[2][m][0] + red[3][m][0];
      const size_t pidx = (size_t)b * NP + m0 + m;
      const float msk = mask[pidx];
      out0[pidx * 2 + 0] = p_in[pidx * 2 + 0] * 4.0f;
      out0[pidx * 2 + 1] = p_in[pidx * 2 + 1] * 4.0f;
      out0[(size_t)2 * NB * NP + pidx] = (s + b3[0]) * msk;
    }
  }
}

extern "C" void kernel_launch(void* const* d_in, const int* in_sizes, int n_in,
                              void* d_out, int out_size, void* d_ws,
                              size_t ws_size, hipStream_t stream) {
  const float* image = (const float*)d_in[0];
  const float* pred  = (const float*)d_in[1];
  const float* mask  = (const float*)d_in[2];
  const float* bw    = (const float*)d_in[3];
  const float* bb    = (const float*)d_in[4];
  const float* oW1   = (const float*)d_in[5];
  const float* ob1   = (const float*)d_in[6];
  const float* oW2   = (const float*)d_in[7];
  const float* ob2   = (const float*)d_in[8];
  const float* oW3   = (const float*)d_in[9];
  const float* ob3   = (const float*)d_in[10];
  const float* cW1   = (const float*)d_in[11];
  const float* cb1   = (const float*)d_in[12];
  const float* cW2   = (const float*)d_in[13];
  const float* cb2   = (const float*)d_in[14];
  const float* cW3   = (const float*)d_in[15];
  const float* cb3   = (const float*)d_in[16];
  float* out = (float*)d_out;

  char* ws = (char*)d_ws;
  unsigned char* feat = (unsigned char*)ws;                // fp8, 25.2 MB
  const size_t featB = (size_t)NB * FH * FW * NC;
  float* pyA  = (float*)(ws + featB);
  float* pyB  = pyA + (size_t)NB * NP * 2;
  unsigned* mins4 = (unsigned*)(pyB + (size_t)NB * NP * 2);  // [4][16] encoded
  __hip_bfloat16* w1c = (__hip_bfloat16*)(mins4 + 64);    // 4 x W1FRAG
  __hip_bfloat16* w2c = w1c + (size_t)4 * W1FRAG;         // 4 x W2FRAG
  __hip_bfloat16* wcb = w2c + (size_t)4 * W2FRAG;         // [192][64]

  prep_all_kernel<<<dim3(1024, 4), 256, 0, stream>>>(
      oW1, cW1, oW2, cW2, bw, pred, mask, w1c, w2c, wcb, mins4);
  conv_kernel<<<dim3(NB * 16384 / 64), 256, 0, stream>>>(image, wcb, bb, feat);

  const float* cur = pred;
  float* nxt = pyA;
  for (int i = 0; i < 3; ++i) {
    mlp_kernel<false><<<dim3(NB * NP / 64), 256, 0, stream>>>(
        feat, cur, mask, mins4 + i * 16,
        (i < 2) ? (mins4 + (i + 1) * 16) : nullptr,
        w1c + (size_t)i * W1FRAG, ob1 + (size_t)i * NSTATE,
        w2c + (size_t)i * W2FRAG, ob2 + (size_t)i * NSTATE,
        oW3 + (size_t)i * 2 * NSTATE, ob3 + (size_t)i * 2, nxt);
    cur = nxt;
    nxt = (nxt == pyA) ? pyB : pyA;
  }
  mlp_kernel<true><<<dim3(NB * NP / 64), 256, 0, stream>>>(
      feat, cur, mask, nullptr, nullptr, w1c + (size_t)3 * W1FRAG, cb1,
      w2c + (size_t)3 * W2FRAG, cb2, cW3, cb3, out);
}